// Round 9
// baseline (278.798 us; speedup 1.0000x reference)
//
#include <hip/hip_runtime.h>
#include <hip/hip_fp16.h>
#include <math.h>

#define FEAT 128
#define NBLK 256       // blocks for bucket hist/scatter
#define BSHIFT 8       // bucket = dst >> 8 (256 nodes per bucket)

typedef _Float16 f16x8 __attribute__((ext_vector_type(8)));
typedef float f32x4 __attribute__((ext_vector_type(4)));

__device__ __forceinline__ float eluf(float x) {
  return x > 0.0f ? x : (__expf(x) - 1.0f);
}

// ---------------- generic scan kernels (1024 elems/block) ----------------

__global__ __launch_bounds__(256) void scan1_kernel(const int* __restrict__ cnt,
                                                    int* __restrict__ pre,
                                                    int* __restrict__ bsum, int n) {
  __shared__ int sd[256];
  const int t = threadIdx.x;
  const int idx = blockIdx.x * 1024 + t * 4;
  int4 v = make_int4(0, 0, 0, 0);
  if (idx + 3 < n) {
    v = *(const int4*)(cnt + idx);
  } else {
    if (idx < n)     v.x = cnt[idx];
    if (idx + 1 < n) v.y = cnt[idx + 1];
    if (idx + 2 < n) v.z = cnt[idx + 2];
    if (idx + 3 < n) v.w = cnt[idx + 3];
  }
  const int tsum = v.x + v.y + v.z + v.w;
  sd[t] = tsum;
  __syncthreads();
  for (int o = 1; o < 256; o <<= 1) {
    int x = (t >= o) ? sd[t - o] : 0;
    __syncthreads();
    sd[t] += x;
    __syncthreads();
  }
  const int excl = sd[t] - tsum;
  if (idx < n)     pre[idx]     = excl;
  if (idx + 1 < n) pre[idx + 1] = excl + v.x;
  if (idx + 2 < n) pre[idx + 2] = excl + v.x + v.y;
  if (idx + 3 < n) pre[idx + 3] = excl + v.x + v.y + v.z;
  if (t == 255) bsum[blockIdx.x] = sd[255];
}

__global__ __launch_bounds__(256) void scan2_kernel(int* __restrict__ bsum, int nb) {
  __shared__ int sd[256];
  const int t = threadIdx.x;
  int v = (t < nb) ? bsum[t] : 0;
  sd[t] = v;
  __syncthreads();
  for (int o = 1; o < 256; o <<= 1) {
    int x = (t >= o) ? sd[t - o] : 0;
    __syncthreads();
    sd[t] += x;
    __syncthreads();
  }
  if (t < nb) bsum[t] = sd[t] - v;
}

// ---------------- bucketed CSR build ----------------
__global__ __launch_bounds__(256) void bucket_hist_kernel(
    const int* __restrict__ ei, int* __restrict__ gh,
    int E, int ET, int nbuck, int chunk) {
  __shared__ int h[512];
  const int t = threadIdx.x;
  const int b = blockIdx.x;
  h[t] = 0; h[t + 256] = 0;
  __syncthreads();
  const int lo = b * chunk;
  const int hi = min(lo + chunk, ET);
  for (int i = lo + t; i < hi; i += 256) {
    int d = (i < E) ? ei[E + i] : (i - E);
    atomicAdd(&h[d >> BSHIFT], 1);
  }
  __syncthreads();
  for (int k = t; k < nbuck; k += 256) gh[k * NBLK + b] = h[k];
}

__global__ __launch_bounds__(256) void bucket_scatter_kernel(
    const int* __restrict__ ei, const int* __restrict__ ghp,
    const int* __restrict__ bsum, unsigned* __restrict__ pairs,
    int E, int ET, int nbuck, int chunk) {
  __shared__ int cur[512];
  const int t = threadIdx.x;
  const int b = blockIdx.x;
  for (int k = t; k < nbuck; k += 256) {
    int idx = k * NBLK + b;
    cur[k] = ghp[idx] + bsum[idx >> 10];
  }
  __syncthreads();
  const int lo = b * chunk;
  const int hi = min(lo + chunk, ET);
  for (int i = lo + t; i < hi; i += 256) {
    int s, d;
    if (i < E) { s = ei[i]; d = ei[E + i]; } else { s = d = i - E; }
    int pos = atomicAdd(&cur[d >> BSHIFT], 1);
    pairs[pos] = ((unsigned)s << 8) | (unsigned)(d & 255);
  }
}

__global__ __launch_bounds__(256) void bucket_finalize_kernel(
    const unsigned* __restrict__ pairs, const int* __restrict__ ghp,
    const int* __restrict__ bsum, int* __restrict__ row_ptr,
    int* __restrict__ esrc, int N, int ET, int nbuck) {
  __shared__ int hist[256];
  __shared__ int cur[256];
  __shared__ int sd[256];
  const int t = threadIdx.x;
  const int k = blockIdx.x;
  const int node0 = k << BSHIFT;
  const int idx0 = k * NBLK;
  const int base = ghp[idx0] + bsum[idx0 >> 10];
  int end;
  if (k + 1 < nbuck) {
    const int idx1 = (k + 1) * NBLK;
    end = ghp[idx1] + bsum[idx1 >> 10];
  } else {
    end = ET;
  }
  hist[t] = 0;
  __syncthreads();
  for (int e = base + t; e < end; e += 256) {
    atomicAdd(&hist[pairs[e] & 255u], 1);
  }
  __syncthreads();
  const int v = hist[t];
  __syncthreads();
  sd[t] = v;
  __syncthreads();
  for (int o = 1; o < 256; o <<= 1) {
    int x = (t >= o) ? sd[t - o] : 0;
    __syncthreads();
    sd[t] += x;
    __syncthreads();
  }
  const int excl = sd[t] - v;
  if (node0 + t < N) row_ptr[node0 + t] = base + excl;
  cur[t] = excl;
  __syncthreads();
  for (int e = base + t; e < end; e += 256) {
    unsigned p = pairs[e];
    int pos = atomicAdd(&cur[p & 255u], 1);
    esrc[base + pos] = (int)(p >> 8);
  }
  if (k == 0 && t == 0) row_ptr[N] = ET;
}

// ---------------- W fragment prepack ----------------
// frag layout: [kstep(4)][tile(9)][lane(64)][elem(8)] fp16.
// tile t covers cols 16t+0..15 of B' = [W | log2e*W@a_src^T | log2e*W@a_dst^T | pad].
__global__ __launch_bounds__(256) void pack_w_kernel(
    const float* __restrict__ W, const float* __restrict__ a_src,
    const float* __restrict__ a_dst, __half* __restrict__ frag) {
  const float LOG2E = 1.4426950408889634f;
  int tid = blockIdx.x * 256 + threadIdx.x;
  if (tid >= 4 * 9 * 64) return;
  int lane = tid & 63;
  int tile = (tid >> 6) % 9;
  int ks = tid / (9 * 64);
  int li = lane & 15, hi = lane >> 4;
  int col = tile * 16 + li;
  __half* dst = frag + (size_t)tid * 8;
  for (int i = 0; i < 8; ++i) {
    int k = ks * 32 + hi * 8 + i;
    float v = 0.f;
    if (col < 128) {
      v = W[k * 128 + col];
    } else if (col < 132) {
      int h = col - 128;
      float s = 0.f;
      for (int j = 0; j < 32; ++j) s += W[k * 128 + h * 32 + j] * a_src[h * 32 + j];
      v = s * LOG2E;
    } else if (col < 136) {
      int h = col - 132;
      float s = 0.f;
      for (int j = 0; j < 32; ++j) s += W[k * 128 + h * 32 + j] * a_dst[h * 32 + j];
      v = s * LOG2E;
    }
    dst[i] = __float2half(v);
  }
}

// ---------------- MFMA GEMM: h = in @ W (+ fused alpha columns) ----------------
// One wave per 16-row tile (round-6 structure; 2-tile/wave regressed occupancy).
template <bool F32IN>
__global__ __launch_bounds__(256) void gemm_mfma_kernel(
    const void* __restrict__ in, const __half* __restrict__ frag,
    __half* __restrict__ hout, float* __restrict__ as_out, float* __restrict__ ad_out,
    int nrows) {
  const int wid = (blockIdx.x * 256 + threadIdx.x) >> 6;
  const int lane = threadIdx.x & 63;
  const int li = lane & 15, hi = lane >> 4;
  int row = wid * 16 + li;
  const bool valid = row < nrows;
  if (wid * 16 >= nrows) return;
  if (!valid) row = nrows - 1;  // safe load, stores predicated

  const f16x8* fragv = (const f16x8*)frag;

  f32x4 acc[9];
#pragma unroll
  for (int t = 0; t < 9; ++t) acc[t] = (f32x4){0.f, 0.f, 0.f, 0.f};

#pragma unroll
  for (int ks = 0; ks < 4; ++ks) {
    f16x8 xf;
    if (F32IN) {
      const float* xp = (const float*)in + (size_t)row * FEAT + ks * 32 + hi * 8;
      float4 v0 = *(const float4*)xp;
      float4 v1 = *(const float4*)(xp + 4);
      xf[0] = (_Float16)v0.x; xf[1] = (_Float16)v0.y;
      xf[2] = (_Float16)v0.z; xf[3] = (_Float16)v0.w;
      xf[4] = (_Float16)v1.x; xf[5] = (_Float16)v1.y;
      xf[6] = (_Float16)v1.z; xf[7] = (_Float16)v1.w;
    } else {
      xf = *(const f16x8*)((const __half*)in + (size_t)row * FEAT + ks * 32 + hi * 8);
    }
#pragma unroll
    for (int t = 0; t < 9; ++t) {
      f16x8 wf = fragv[(ks * 9 + t) * 64 + lane];
      acc[t] = __builtin_amdgcn_mfma_f32_16x16x32_f16(wf, xf, acc[t], 0, 0, 0);
    }
  }

  if (!valid) return;
#pragma unroll
  for (int t = 0; t < 8; ++t) {
    union { __half2 h[2]; uint2 u; } pk;
    pk.h[0] = __floats2half2_rn(acc[t][0], acc[t][1]);
    pk.h[1] = __floats2half2_rn(acc[t][2], acc[t][3]);
    *(uint2*)(hout + (size_t)row * FEAT + t * 16 + hi * 4) = pk.u;
  }
  if (hi == 0) *(float4*)(as_out + row * 4) = make_float4(acc[8][0], acc[8][1], acc[8][2], acc[8][3]);
  if (hi == 1) *(float4*)(ad_out + row * 4) = make_float4(acc[8][0], acc[8][1], acc[8][2], acc[8][3]);
}

// ---------------- per-node softmax + aggregation ----------------
// One wave per node. 16-edge chunks, producer/consumer via LDS *broadcast reads*
// (NOT bpermute - its lane-crossbar serialized in round 7):
//  producer: lane l=(g=l>>4, j=l&15) computes w for (edge j, head g): one exp per
//            (edge,head); accumulates private den partial (group-reduced at end).
//  distribute: ds_write w at lane slot; consumers ds_read wbuf[g*16+k] - 4 distinct
//            addresses per wave = broadcast + free 2-way bank alias.
//  gather: src ids -> SGPR via readlane, h addressed as SGPR-base + const voffset
//            (addressing on SALU); all 16 loads issued before consumption.
// MODE 0: write fp16 elu(agg + bias). MODE 1: fused FC head.
template <int MODE>
__global__ __launch_bounds__(256) void node_gat_kernel(
    const int* __restrict__ row_ptr, const int* __restrict__ esrc,
    const float* __restrict__ as_, const float* __restrict__ ad_,
    const __half2* __restrict__ h, const float* __restrict__ bias,
    __half2* __restrict__ out16, const float* __restrict__ fcw,
    const float* __restrict__ fcb, float* __restrict__ outf, int n) {
  __shared__ float wbuf[4][64];
  const int wib = threadIdx.x >> 6;       // wave within block
  const int wid = (blockIdx.x * 256 + threadIdx.x) >> 6;
  if (wid >= n) return;
  const int l = threadIdx.x & 63;
  const int g = l >> 4;                   // head (producer & consumer)
  const int j = l & 15;                   // producer edge slot
  const int begin = row_ptr[wid];
  const int end = row_ptr[wid + 1];
  const float adv = ad_[(unsigned)wid * 4u + (unsigned)g];
  float* wslot = &wbuf[wib][0];
  const int rbase = g * 16;

  float2 a2 = make_float2(0.f, 0.f);
  float denp = 0.f;   // per-lane partial; reduced over the 16-lane head group at end

  int e = begin;
  for (; e + 16 <= end; e += 16) {
    // producer: w for (edge j, head g)
    const unsigned s = (unsigned)esrc[e + j];
    const float x = as_[s * 4u + (unsigned)g] + adv;
    const float w = __builtin_amdgcn_exp2f(fmaxf(x, 0.2f * x));
    denp += w;
    wslot[l] = w;                          // ds_write (in-order LDS pipe, same wave)
    // broadcast srcs -> SGPR, issue all 16 h gathers (SALU addressing)
    __half2 hv[16];
#pragma unroll
    for (int k = 0; k < 16; ++k) {
      const unsigned sk = (unsigned)__builtin_amdgcn_readlane((int)s, k);
      hv[k] = h[((size_t)sk << 6) | (unsigned)l];
    }
#pragma unroll
    for (int k = 0; k < 16; ++k) {
      const float wk = wslot[rbase + k];   // ds_read broadcast (same addr per group)
      a2.x = fmaf(__half2float(hv[k].x), wk, a2.x);
      a2.y = fmaf(__half2float(hv[k].y), wk, a2.y);
    }
  }
  // remainder (< 16 edges): masked producer, dynamic consumer loop
  const int rem = end - e;
  if (rem > 0) {
    unsigned s = 0;
    float w = 0.f;
    if (j < rem) {
      s = (unsigned)esrc[e + j];
      const float x = as_[s * 4u + (unsigned)g] + adv;
      w = __builtin_amdgcn_exp2f(fmaxf(x, 0.2f * x));
      denp += w;
    }
    wslot[l] = w;
    for (int k = 0; k < rem; ++k) {
      const unsigned sk = (unsigned)__builtin_amdgcn_readlane((int)s, k);
      const __half2 hk = h[((size_t)sk << 6) | (unsigned)l];
      const float wk = wslot[rbase + k];
      a2.x = fmaf(__half2float(hk.x), wk, a2.x);
      a2.y = fmaf(__half2float(hk.y), wk, a2.y);
    }
  }

  // reduce den over the 16-lane head group
  float den = denp;
  den += __shfl_xor(den, 1);
  den += __shfl_xor(den, 2);
  den += __shfl_xor(den, 4);
  den += __shfl_xor(den, 8);

  const float inv = 1.0f / (den + 1e-16f);
  const float o0 = a2.x * inv;
  const float o1 = a2.y * inv;
  const float2 b = *(const float2*)(bias + l * 2);
  if (MODE == 0) {
    out16[((size_t)(unsigned)wid << 6) | (unsigned)l] =
        __floats2half2_rn(eluf(o0 + b.x), eluf(o1 + b.y));
  } else {
    const float e0 = eluf(o0 + b.x);
    const float e1 = eluf(o1 + b.y);
    const float4 w4 = *(const float4*)(fcw + l * 4);  // Wfc[2l][0..1], Wfc[2l+1][0..1]
    float s0 = e0 * w4.x + e1 * w4.z;
    float s1 = e0 * w4.y + e1 * w4.w;
#pragma unroll
    for (int o = 32; o >= 1; o >>= 1) {
      s0 += __shfl_xor(s0, o);
      s1 += __shfl_xor(s1, o);
    }
    if (l == 0) {
      *(float2*)(outf + (size_t)wid * 2) = make_float2(s0 + fcb[0], s1 + fcb[1]);
    }
  }
}

extern "C" void kernel_launch(void* const* d_in, const int* in_sizes, int n_in,
                              void* d_out, int out_size, void* d_ws, size_t ws_size,
                              hipStream_t stream) {
  const float* x   = (const float*)d_in[0];
  const int*   ei  = (const int*)d_in[1];
  const float* W1  = (const float*)d_in[2];
  const float* as1 = (const float*)d_in[3];
  const float* ad1 = (const float*)d_in[4];
  const float* b1  = (const float*)d_in[5];
  const float* W2  = (const float*)d_in[6];
  const float* as2 = (const float*)d_in[7];
  const float* ad2 = (const float*)d_in[8];
  const float* b2  = (const float*)d_in[9];
  const float* Wfc = (const float*)d_in[10];
  const float* bfc = (const float*)d_in[11];
  float* out = (float*)d_out;

  const int N = in_sizes[0] / FEAT;
  const int E = in_sizes[1] / 2;
  const int ET = E + N;
  const int nbuck = (N + 255) >> BSHIFT;     // buckets of 256 nodes
  const int NN = nbuck * NBLK;               // gh array length
  const int chunk = (ET + NBLK - 1) / NBLK;

  // workspace layout
  char* ws = (char*)d_ws;
  __half* hraw = (__half*)ws;                               // N*128 fp16
  __half* hin2 = hraw + (size_t)N * FEAT;                   // N*128 fp16
  float* acc   = (float*)(hin2 + (size_t)N * FEAT);         // N*128 f32 (CSR scratch)
  float* asb   = acc + (size_t)N * FEAT;                    // N*4
  float* adb   = asb + (size_t)N * 4;                       // N*4
  __half* bfrag1 = (__half*)(adb + (size_t)N * 4);          // 4*9*64*8 fp16
  __half* bfrag2 = bfrag1 + 4 * 9 * 64 * 8;                 // 4*9*64*8 fp16
  int* bsum    = (int*)(bfrag2 + 4 * 9 * 64 * 8);           // 256
  int* row_ptr = bsum + 256;                                // N+1
  int* esrc    = row_ptr + (N + 1);                         // ET
  // CSR-build scratch aliased into acc region (dead after finalize):
  int* gh    = (int*)acc;                                   // NN
  int* ghp   = gh + NN;                                     // NN
  unsigned* pairs = (unsigned*)(ghp + NN);                  // ET

  const dim3 b256(256);
  const int nb = (NN + 1023) / 1024;

  // ---- prepack W fragments ----
  pack_w_kernel<<<9, b256, 0, stream>>>(W1, as1, ad1, bfrag1);
  pack_w_kernel<<<9, b256, 0, stream>>>(W2, as2, ad2, bfrag2);

  // ---- bucketed CSR build ----
  bucket_hist_kernel<<<NBLK, b256, 0, stream>>>(ei, gh, E, ET, nbuck, chunk);
  scan1_kernel<<<nb, b256, 0, stream>>>(gh, ghp, bsum, NN);
  scan2_kernel<<<1, b256, 0, stream>>>(bsum, nb);
  bucket_scatter_kernel<<<NBLK, b256, 0, stream>>>(ei, ghp, bsum, pairs, E, ET, nbuck, chunk);
  bucket_finalize_kernel<<<nbuck, b256, 0, stream>>>(pairs, ghp, bsum, row_ptr, esrc, N, ET, nbuck);

  const int ntiles = (N + 15) / 16;
  const int ggrid = (ntiles + 3) / 4;          // 1 tile/wave, 4 waves/block
  const int wgrid = (N * 64 + 255) / 256;      // one wave per node

  // ---- layer 1 ----
  gemm_mfma_kernel<true><<<ggrid, b256, 0, stream>>>(x, bfrag1, hraw, asb, adb, N);
  node_gat_kernel<0><<<wgrid, b256, 0, stream>>>(row_ptr, esrc, asb, adb,
                                                 (const __half2*)hraw, b1,
                                                 (__half2*)hin2, nullptr, nullptr, nullptr, N);

  // ---- layer 2 (FC head fused) ----
  gemm_mfma_kernel<false><<<ggrid, b256, 0, stream>>>(hin2, bfrag2, hraw, asb, adb, N);
  node_gat_kernel<1><<<wgrid, b256, 0, stream>>>(row_ptr, esrc, asb, adb,
                                                 (const __half2*)hraw, b2,
                                                 nullptr, Wfc, bfc, out, N);
}

// Round 10
// 268.361 us; speedup vs baseline: 1.0389x; 1.0389x over previous
//
#include <hip/hip_runtime.h>
#include <hip/hip_fp16.h>
#include <math.h>

#define FEAT 128
#define NBLK 256       // blocks for bucket hist/scatter
#define BSHIFT 8       // bucket = dst >> 8 (256 nodes per bucket)

typedef _Float16 f16x8 __attribute__((ext_vector_type(8)));
typedef float f32x4 __attribute__((ext_vector_type(4)));

__device__ __forceinline__ float eluf(float x) {
  return x > 0.0f ? x : (__expf(x) - 1.0f);
}

// ---------------- generic scan kernels (1024 elems/block) ----------------

__global__ __launch_bounds__(256) void scan1_kernel(const int* __restrict__ cnt,
                                                    int* __restrict__ pre,
                                                    int* __restrict__ bsum, int n) {
  __shared__ int sd[256];
  const int t = threadIdx.x;
  const int idx = blockIdx.x * 1024 + t * 4;
  int4 v = make_int4(0, 0, 0, 0);
  if (idx + 3 < n) {
    v = *(const int4*)(cnt + idx);
  } else {
    if (idx < n)     v.x = cnt[idx];
    if (idx + 1 < n) v.y = cnt[idx + 1];
    if (idx + 2 < n) v.z = cnt[idx + 2];
    if (idx + 3 < n) v.w = cnt[idx + 3];
  }
  const int tsum = v.x + v.y + v.z + v.w;
  sd[t] = tsum;
  __syncthreads();
  for (int o = 1; o < 256; o <<= 1) {
    int x = (t >= o) ? sd[t - o] : 0;
    __syncthreads();
    sd[t] += x;
    __syncthreads();
  }
  const int excl = sd[t] - tsum;
  if (idx < n)     pre[idx]     = excl;
  if (idx + 1 < n) pre[idx + 1] = excl + v.x;
  if (idx + 2 < n) pre[idx + 2] = excl + v.x + v.y;
  if (idx + 3 < n) pre[idx + 3] = excl + v.x + v.y + v.z;
  if (t == 255) bsum[blockIdx.x] = sd[255];
}

__global__ __launch_bounds__(256) void scan2_kernel(int* __restrict__ bsum, int nb) {
  __shared__ int sd[256];
  const int t = threadIdx.x;
  int v = (t < nb) ? bsum[t] : 0;
  sd[t] = v;
  __syncthreads();
  for (int o = 1; o < 256; o <<= 1) {
    int x = (t >= o) ? sd[t - o] : 0;
    __syncthreads();
    sd[t] += x;
    __syncthreads();
  }
  if (t < nb) bsum[t] = sd[t] - v;
}

// ---------------- bucketed CSR build ----------------
__global__ __launch_bounds__(256) void bucket_hist_kernel(
    const int* __restrict__ ei, int* __restrict__ gh,
    int E, int ET, int nbuck, int chunk) {
  __shared__ int h[512];
  const int t = threadIdx.x;
  const int b = blockIdx.x;
  h[t] = 0; h[t + 256] = 0;
  __syncthreads();
  const int lo = b * chunk;
  const int hi = min(lo + chunk, ET);
  for (int i = lo + t; i < hi; i += 256) {
    int d = (i < E) ? ei[E + i] : (i - E);
    atomicAdd(&h[d >> BSHIFT], 1);
  }
  __syncthreads();
  for (int k = t; k < nbuck; k += 256) gh[k * NBLK + b] = h[k];
}

__global__ __launch_bounds__(256) void bucket_scatter_kernel(
    const int* __restrict__ ei, const int* __restrict__ ghp,
    const int* __restrict__ bsum, unsigned* __restrict__ pairs,
    int E, int ET, int nbuck, int chunk) {
  __shared__ int cur[512];
  const int t = threadIdx.x;
  const int b = blockIdx.x;
  for (int k = t; k < nbuck; k += 256) {
    int idx = k * NBLK + b;
    cur[k] = ghp[idx] + bsum[idx >> 10];
  }
  __syncthreads();
  const int lo = b * chunk;
  const int hi = min(lo + chunk, ET);
  for (int i = lo + t; i < hi; i += 256) {
    int s, d;
    if (i < E) { s = ei[i]; d = ei[E + i]; } else { s = d = i - E; }
    int pos = atomicAdd(&cur[d >> BSHIFT], 1);
    pairs[pos] = ((unsigned)s << 8) | (unsigned)(d & 255);
  }
}

__global__ __launch_bounds__(256) void bucket_finalize_kernel(
    const unsigned* __restrict__ pairs, const int* __restrict__ ghp,
    const int* __restrict__ bsum, int* __restrict__ row_ptr,
    int* __restrict__ esrc, int N, int ET, int nbuck) {
  __shared__ int hist[256];
  __shared__ int cur[256];
  __shared__ int sd[256];
  const int t = threadIdx.x;
  const int k = blockIdx.x;
  const int node0 = k << BSHIFT;
  const int idx0 = k * NBLK;
  const int base = ghp[idx0] + bsum[idx0 >> 10];
  int end;
  if (k + 1 < nbuck) {
    const int idx1 = (k + 1) * NBLK;
    end = ghp[idx1] + bsum[idx1 >> 10];
  } else {
    end = ET;
  }
  hist[t] = 0;
  __syncthreads();
  for (int e = base + t; e < end; e += 256) {
    atomicAdd(&hist[pairs[e] & 255u], 1);
  }
  __syncthreads();
  const int v = hist[t];
  __syncthreads();
  sd[t] = v;
  __syncthreads();
  for (int o = 1; o < 256; o <<= 1) {
    int x = (t >= o) ? sd[t - o] : 0;
    __syncthreads();
    sd[t] += x;
    __syncthreads();
  }
  const int excl = sd[t] - v;
  if (node0 + t < N) row_ptr[node0 + t] = base + excl;
  cur[t] = excl;
  __syncthreads();
  for (int e = base + t; e < end; e += 256) {
    unsigned p = pairs[e];
    int pos = atomicAdd(&cur[p & 255u], 1);
    esrc[base + pos] = (int)(p >> 8);
  }
  if (k == 0 && t == 0) row_ptr[N] = ET;
}

// ---------------- W fragment prepack (both layers, one launch) ----------------
// frag layout: [kstep(4)][tile(9)][lane(64)][elem(8)] fp16.
// tile t covers cols 16t+0..15 of B' = [W | log2e*W@a_src^T | log2e*W@a_dst^T | pad].
__global__ __launch_bounds__(256) void pack_w_kernel(
    const float* __restrict__ W1, const float* __restrict__ as1,
    const float* __restrict__ ad1, __half* __restrict__ frag1,
    const float* __restrict__ W2, const float* __restrict__ as2,
    const float* __restrict__ ad2, __half* __restrict__ frag2) {
  const float LOG2E = 1.4426950408889634f;
  int tid = blockIdx.x * 256 + threadIdx.x;
  const int PER = 4 * 9 * 64;
  if (tid >= 2 * PER) return;
  const bool second = tid >= PER;
  if (second) tid -= PER;
  const float* W = second ? W2 : W1;
  const float* a_src = second ? as2 : as1;
  const float* a_dst = second ? ad2 : ad1;
  __half* frag = second ? frag2 : frag1;
  int lane = tid & 63;
  int tile = (tid >> 6) % 9;
  int ks = tid / (9 * 64);
  int li = lane & 15, hi = lane >> 4;
  int col = tile * 16 + li;
  __half* dst = frag + (size_t)tid * 8;
  for (int i = 0; i < 8; ++i) {
    int k = ks * 32 + hi * 8 + i;
    float v = 0.f;
    if (col < 128) {
      v = W[k * 128 + col];
    } else if (col < 132) {
      int h = col - 128;
      float s = 0.f;
      for (int j = 0; j < 32; ++j) s += W[k * 128 + h * 32 + j] * a_src[h * 32 + j];
      v = s * LOG2E;
    } else if (col < 136) {
      int h = col - 132;
      float s = 0.f;
      for (int j = 0; j < 32; ++j) s += W[k * 128 + h * 32 + j] * a_dst[h * 32 + j];
      v = s * LOG2E;
    }
    dst[i] = __float2half(v);
  }
}

// ---------------- MFMA GEMM: h = in @ W (+ fused alpha columns) ----------------
// One wave per 16-row tile (1 tile/wave; 2-tile/wave regressed occupancy in r8).
template <bool F32IN>
__global__ __launch_bounds__(256) void gemm_mfma_kernel(
    const void* __restrict__ in, const __half* __restrict__ frag,
    __half* __restrict__ hout, float* __restrict__ as_out, float* __restrict__ ad_out,
    int nrows) {
  const int wid = (blockIdx.x * 256 + threadIdx.x) >> 6;
  const int lane = threadIdx.x & 63;
  const int li = lane & 15, hi = lane >> 4;
  int row = wid * 16 + li;
  const bool valid = row < nrows;
  if (wid * 16 >= nrows) return;
  if (!valid) row = nrows - 1;  // safe load, stores predicated

  const f16x8* fragv = (const f16x8*)frag;

  f32x4 acc[9];
#pragma unroll
  for (int t = 0; t < 9; ++t) acc[t] = (f32x4){0.f, 0.f, 0.f, 0.f};

#pragma unroll
  for (int ks = 0; ks < 4; ++ks) {
    f16x8 xf;
    if (F32IN) {
      const float* xp = (const float*)in + (size_t)row * FEAT + ks * 32 + hi * 8;
      float4 v0 = *(const float4*)xp;
      float4 v1 = *(const float4*)(xp + 4);
      xf[0] = (_Float16)v0.x; xf[1] = (_Float16)v0.y;
      xf[2] = (_Float16)v0.z; xf[3] = (_Float16)v0.w;
      xf[4] = (_Float16)v1.x; xf[5] = (_Float16)v1.y;
      xf[6] = (_Float16)v1.z; xf[7] = (_Float16)v1.w;
    } else {
      xf = *(const f16x8*)((const __half*)in + (size_t)row * FEAT + ks * 32 + hi * 8);
    }
#pragma unroll
    for (int t = 0; t < 9; ++t) {
      f16x8 wf = fragv[(ks * 9 + t) * 64 + lane];
      acc[t] = __builtin_amdgcn_mfma_f32_16x16x32_f16(wf, xf, acc[t], 0, 0, 0);
    }
  }

  if (!valid) return;
#pragma unroll
  for (int t = 0; t < 8; ++t) {
    union { __half2 h[2]; uint2 u; } pk;
    pk.h[0] = __floats2half2_rn(acc[t][0], acc[t][1]);
    pk.h[1] = __floats2half2_rn(acc[t][2], acc[t][3]);
    *(uint2*)(hout + (size_t)row * FEAT + t * 16 + hi * 4) = pk.u;
  }
  if (hi == 0) *(float4*)(as_out + row * 4) = make_float4(acc[8][0], acc[8][1], acc[8][2], acc[8][3]);
  if (hi == 1) *(float4*)(ad_out + row * 4) = make_float4(acc[8][0], acc[8][1], acc[8][2], acc[8][3]);
}

// ---------------- per-node softmax + aggregation ----------------
// Round-8 accumulate body (8-deep gather chunks, u32 saddr addressing, exp2;
// alphas pre-scaled by log2e in pack_w). Extracted so both kernels share it.
__device__ __forceinline__ void gat_accum(
    const int* __restrict__ esrc, const float* __restrict__ as_,
    const __half2* __restrict__ h, float adv, unsigned hd, unsigned lofs,
    int e, int end, float2& a2, float& den) {
  for (; e + 7 < end; e += 8) {
    unsigned s[8];
#pragma unroll
    for (int i = 0; i < 8; ++i) s[i] = (unsigned)esrc[e + i];
    float as8[8];
#pragma unroll
    for (int i = 0; i < 8; ++i) as8[i] = as_[s[i] * 4u + hd];
    __half2 hv[8];
#pragma unroll
    for (int i = 0; i < 8; ++i) hv[i] = h[((size_t)s[i] << 6) | lofs];
#pragma unroll
    for (int i = 0; i < 8; ++i) {
      const float x = as8[i] + adv;
      const float w = __builtin_amdgcn_exp2f(fmaxf(x, 0.2f * x));
      den += w;
      a2.x = fmaf(__half2float(hv[i].x), w, a2.x);
      a2.y = fmaf(__half2float(hv[i].y), w, a2.y);
    }
  }
  for (; e + 3 < end; e += 4) {
    unsigned s[4];
#pragma unroll
    for (int i = 0; i < 4; ++i) s[i] = (unsigned)esrc[e + i];
    float as4[4];
#pragma unroll
    for (int i = 0; i < 4; ++i) as4[i] = as_[s[i] * 4u + hd];
    __half2 hv[4];
#pragma unroll
    for (int i = 0; i < 4; ++i) hv[i] = h[((size_t)s[i] << 6) | lofs];
#pragma unroll
    for (int i = 0; i < 4; ++i) {
      const float x = as4[i] + adv;
      const float w = __builtin_amdgcn_exp2f(fmaxf(x, 0.2f * x));
      den += w;
      a2.x = fmaf(__half2float(hv[i].x), w, a2.x);
      a2.y = fmaf(__half2float(hv[i].y), w, a2.y);
    }
  }
  for (; e < end; ++e) {
    const unsigned s0 = (unsigned)esrc[e];
    const float x = as_[s0 * 4u + hd] + adv;
    const float w = __builtin_amdgcn_exp2f(fmaxf(x, 0.2f * x));
    const __half2 h0 = h[((size_t)s0 << 6) | lofs];
    den += w;
    a2.x = fmaf(__half2float(h0.x), w, a2.x);
    a2.y = fmaf(__half2float(h0.y), w, a2.y);
  }
}

// Single-node wave (round-8 exact structure). MODE 1 = fused FC head.
template <int MODE>
__global__ __launch_bounds__(256) void node_gat_kernel(
    const int* __restrict__ row_ptr, const int* __restrict__ esrc,
    const float* __restrict__ as_, const float* __restrict__ ad_,
    const __half2* __restrict__ h, const float* __restrict__ bias,
    __half2* __restrict__ out16, const float* __restrict__ fcw,
    const float* __restrict__ fcb, float* __restrict__ outf, int n) {
  const int wid = (blockIdx.x * 256 + threadIdx.x) >> 6;
  if (wid >= n) return;
  const int l = threadIdx.x & 63;
  const unsigned hd = (unsigned)(l >> 4);
  const unsigned lofs = (unsigned)l;
  const int begin = row_ptr[wid];
  const int end = row_ptr[wid + 1];
  const float adv = ad_[(unsigned)wid * 4u + hd];

  float2 a2 = make_float2(0.f, 0.f);
  float den = 0.f;
  gat_accum(esrc, as_, h, adv, hd, lofs, begin, end, a2, den);

  const float inv = 1.0f / (den + 1e-16f);
  const float o0 = a2.x * inv;
  const float o1 = a2.y * inv;
  const float2 b = *(const float2*)(bias + l * 2);
  if (MODE == 0) {
    out16[((size_t)(unsigned)wid << 6) | lofs] =
        __floats2half2_rn(eluf(o0 + b.x), eluf(o1 + b.y));
  } else {
    const float e0 = eluf(o0 + b.x);
    const float e1 = eluf(o1 + b.y);
    const float4 w4 = *(const float4*)(fcw + l * 4);  // Wfc[2l][0..1], Wfc[2l+1][0..1]
    float s0 = e0 * w4.x + e1 * w4.z;
    float s1 = e0 * w4.y + e1 * w4.w;
#pragma unroll
    for (int o = 32; o >= 1; o >>= 1) {
      s0 += __shfl_xor(s0, o);
      s1 += __shfl_xor(s1, o);
    }
    if (l == 0) {
      *(float2*)(outf + (size_t)wid * 2) = make_float2(s0 + fcb[0], s1 + fcb[1]);
    }
  }
}

// Paired-node wave: 2 adjacent nodes per wave, 16 h-gathers in flight
// (A/B experiment: does 2x miss concurrency raise the ~3.07 TB/s gather rate?)
__global__ __launch_bounds__(256) void node_gat_pair_kernel(
    const int* __restrict__ row_ptr, const int* __restrict__ esrc,
    const float* __restrict__ as_, const float* __restrict__ ad_,
    const __half2* __restrict__ h, const float* __restrict__ bias,
    __half2* __restrict__ out16, int n) {
  const int wpair = (blockIdx.x * 256 + threadIdx.x) >> 6;
  const int wid0 = wpair * 2;
  if (wid0 >= n) return;
  const int wid1 = wid0 + 1;
  const bool has1 = wid1 < n;
  const int l = threadIdx.x & 63;
  const unsigned hd = (unsigned)(l >> 4);
  const unsigned lofs = (unsigned)l;

  const int b0 = row_ptr[wid0];
  const int m0 = row_ptr[wid0 + 1];          // == row_ptr[wid1]
  const int m1 = has1 ? row_ptr[wid1 + 1] : m0;
  const float adv0 = ad_[(unsigned)wid0 * 4u + hd];
  const float adv1 = has1 ? ad_[(unsigned)wid1 * 4u + hd] : 0.f;

  float2 a20 = make_float2(0.f, 0.f), a21 = make_float2(0.f, 0.f);
  float den0 = 0.f, den1 = 0.f;
  int p0 = b0, p1 = m0;

  // paired main loop: 8 edges per node, 16 gathers in flight
  while (p0 + 7 < m0 && p1 + 7 < m1) {
    unsigned s0[8], s1[8];
#pragma unroll
    for (int i = 0; i < 8; ++i) s0[i] = (unsigned)esrc[p0 + i];
#pragma unroll
    for (int i = 0; i < 8; ++i) s1[i] = (unsigned)esrc[p1 + i];
    float as0[8], as1[8];
#pragma unroll
    for (int i = 0; i < 8; ++i) as0[i] = as_[s0[i] * 4u + hd];
#pragma unroll
    for (int i = 0; i < 8; ++i) as1[i] = as_[s1[i] * 4u + hd];
    __half2 hv0[8], hv1[8];
#pragma unroll
    for (int i = 0; i < 8; ++i) hv0[i] = h[((size_t)s0[i] << 6) | lofs];
#pragma unroll
    for (int i = 0; i < 8; ++i) hv1[i] = h[((size_t)s1[i] << 6) | lofs];
#pragma unroll
    for (int i = 0; i < 8; ++i) {
      const float x = as0[i] + adv0;
      const float w = __builtin_amdgcn_exp2f(fmaxf(x, 0.2f * x));
      den0 += w;
      a20.x = fmaf(__half2float(hv0[i].x), w, a20.x);
      a20.y = fmaf(__half2float(hv0[i].y), w, a20.y);
    }
#pragma unroll
    for (int i = 0; i < 8; ++i) {
      const float x = as1[i] + adv1;
      const float w = __builtin_amdgcn_exp2f(fmaxf(x, 0.2f * x));
      den1 += w;
      a21.x = fmaf(__half2float(hv1[i].x), w, a21.x);
      a21.y = fmaf(__half2float(hv1[i].y), w, a21.y);
    }
    p0 += 8;
    p1 += 8;
  }
  // drain remainders per node (round-8 body)
  gat_accum(esrc, as_, h, adv0, hd, lofs, p0, m0, a20, den0);
  if (has1) gat_accum(esrc, as_, h, adv1, hd, lofs, p1, m1, a21, den1);

  const float2 b = *(const float2*)(bias + l * 2);
  {
    const float inv = 1.0f / (den0 + 1e-16f);
    out16[((size_t)(unsigned)wid0 << 6) | lofs] =
        __floats2half2_rn(eluf(a20.x * inv + b.x), eluf(a20.y * inv + b.y));
  }
  if (has1) {
    const float inv = 1.0f / (den1 + 1e-16f);
    out16[((size_t)(unsigned)wid1 << 6) | lofs] =
        __floats2half2_rn(eluf(a21.x * inv + b.x), eluf(a21.y * inv + b.y));
  }
}

extern "C" void kernel_launch(void* const* d_in, const int* in_sizes, int n_in,
                              void* d_out, int out_size, void* d_ws, size_t ws_size,
                              hipStream_t stream) {
  const float* x   = (const float*)d_in[0];
  const int*   ei  = (const int*)d_in[1];
  const float* W1  = (const float*)d_in[2];
  const float* as1 = (const float*)d_in[3];
  const float* ad1 = (const float*)d_in[4];
  const float* b1  = (const float*)d_in[5];
  const float* W2  = (const float*)d_in[6];
  const float* as2 = (const float*)d_in[7];
  const float* ad2 = (const float*)d_in[8];
  const float* b2  = (const float*)d_in[9];
  const float* Wfc = (const float*)d_in[10];
  const float* bfc = (const float*)d_in[11];
  float* out = (float*)d_out;

  const int N = in_sizes[0] / FEAT;
  const int E = in_sizes[1] / 2;
  const int ET = E + N;
  const int nbuck = (N + 255) >> BSHIFT;     // buckets of 256 nodes
  const int NN = nbuck * NBLK;               // gh array length
  const int chunk = (ET + NBLK - 1) / NBLK;

  // workspace layout
  char* ws = (char*)d_ws;
  __half* hraw = (__half*)ws;                               // N*128 fp16
  __half* hin2 = hraw + (size_t)N * FEAT;                   // N*128 fp16
  float* acc   = (float*)(hin2 + (size_t)N * FEAT);         // N*128 f32 (CSR scratch)
  float* asb   = acc + (size_t)N * FEAT;                    // N*4
  float* adb   = asb + (size_t)N * 4;                       // N*4
  __half* bfrag1 = (__half*)(adb + (size_t)N * 4);          // 4*9*64*8 fp16
  __half* bfrag2 = bfrag1 + 4 * 9 * 64 * 8;                 // 4*9*64*8 fp16
  int* bsum    = (int*)(bfrag2 + 4 * 9 * 64 * 8);           // 256
  int* row_ptr = bsum + 256;                                // N+1
  int* esrc    = row_ptr + (N + 1);                         // ET
  // CSR-build scratch aliased into acc region (dead after finalize):
  int* gh    = (int*)acc;                                   // NN
  int* ghp   = gh + NN;                                     // NN
  unsigned* pairs = (unsigned*)(ghp + NN);                  // ET

  const dim3 b256(256);
  const int nb = (NN + 1023) / 1024;

  // ---- prepack W fragments (both layers, one launch) ----
  pack_w_kernel<<<18, b256, 0, stream>>>(W1, as1, ad1, bfrag1, W2, as2, ad2, bfrag2);

  // ---- bucketed CSR build ----
  bucket_hist_kernel<<<NBLK, b256, 0, stream>>>(ei, gh, E, ET, nbuck, chunk);
  scan1_kernel<<<nb, b256, 0, stream>>>(gh, ghp, bsum, NN);
  scan2_kernel<<<1, b256, 0, stream>>>(bsum, nb);
  bucket_scatter_kernel<<<NBLK, b256, 0, stream>>>(ei, ghp, bsum, pairs, E, ET, nbuck, chunk);
  bucket_finalize_kernel<<<nbuck, b256, 0, stream>>>(pairs, ghp, bsum, row_ptr, esrc, N, ET, nbuck);

  const int ntiles = (N + 15) / 16;
  const int ggrid = (ntiles + 3) / 4;            // 1 tile/wave, 4 waves/block
  const int npair = (N + 1) / 2;
  const int pgrid = (npair + 3) / 4;             // paired: 1 wave per 2 nodes
  const int wgrid = (N * 64 + 255) / 256;        // single: 1 wave per node

  // ---- layer 1 (paired-node A arm) ----
  gemm_mfma_kernel<true><<<ggrid, b256, 0, stream>>>(x, bfrag1, hraw, asb, adb, N);
  node_gat_pair_kernel<<<pgrid, b256, 0, stream>>>(row_ptr, esrc, asb, adb,
                                                   (const __half2*)hraw, b1,
                                                   (__half2*)hin2, N);

  // ---- layer 2 (round-8 single-node B arm, FC head fused) ----
  gemm_mfma_kernel<false><<<ggrid, b256, 0, stream>>>(hin2, bfrag2, hraw, asb, adb, N);
  node_gat_kernel<1><<<wgrid, b256, 0, stream>>>(row_ptr, esrc, asb, adb,
                                                 (const __half2*)hraw, b2,
                                                 nullptr, Wfc, bfc, out, N);
}

// Round 11
// 248.545 us; speedup vs baseline: 1.1217x; 1.0797x over previous
//
#include <hip/hip_runtime.h>
#include <hip/hip_fp16.h>
#include <math.h>

#define FEAT 128
#define NBLK 256       // blocks for bucket hist/scatter
#define BSHIFT 8       // bucket = dst >> 8 (256 nodes per bucket)

typedef _Float16 f16x8 __attribute__((ext_vector_type(8)));
typedef float f32x4 __attribute__((ext_vector_type(4)));

__device__ __forceinline__ float eluf(float x) {
  return x > 0.0f ? x : (__expf(x) - 1.0f);
}

// ---------------- generic scan kernels (1024 elems/block) ----------------

__global__ __launch_bounds__(256) void scan1_kernel(const int* __restrict__ cnt,
                                                    int* __restrict__ pre,
                                                    int* __restrict__ bsum, int n) {
  __shared__ int sd[256];
  const int t = threadIdx.x;
  const int idx = blockIdx.x * 1024 + t * 4;
  int4 v = make_int4(0, 0, 0, 0);
  if (idx + 3 < n) {
    v = *(const int4*)(cnt + idx);
  } else {
    if (idx < n)     v.x = cnt[idx];
    if (idx + 1 < n) v.y = cnt[idx + 1];
    if (idx + 2 < n) v.z = cnt[idx + 2];
    if (idx + 3 < n) v.w = cnt[idx + 3];
  }
  const int tsum = v.x + v.y + v.z + v.w;
  sd[t] = tsum;
  __syncthreads();
  for (int o = 1; o < 256; o <<= 1) {
    int x = (t >= o) ? sd[t - o] : 0;
    __syncthreads();
    sd[t] += x;
    __syncthreads();
  }
  const int excl = sd[t] - tsum;
  if (idx < n)     pre[idx]     = excl;
  if (idx + 1 < n) pre[idx + 1] = excl + v.x;
  if (idx + 2 < n) pre[idx + 2] = excl + v.x + v.y;
  if (idx + 3 < n) pre[idx + 3] = excl + v.x + v.y + v.z;
  if (t == 255) bsum[blockIdx.x] = sd[255];
}

__global__ __launch_bounds__(256) void scan2_kernel(int* __restrict__ bsum, int nb) {
  __shared__ int sd[256];
  const int t = threadIdx.x;
  int v = (t < nb) ? bsum[t] : 0;
  sd[t] = v;
  __syncthreads();
  for (int o = 1; o < 256; o <<= 1) {
    int x = (t >= o) ? sd[t - o] : 0;
    __syncthreads();
    sd[t] += x;
    __syncthreads();
  }
  if (t < nb) bsum[t] = sd[t] - v;
}

// ---------------- bucketed CSR build ----------------
__global__ __launch_bounds__(256) void bucket_hist_kernel(
    const int* __restrict__ ei, int* __restrict__ gh,
    int E, int ET, int nbuck, int chunk) {
  __shared__ int h[512];
  const int t = threadIdx.x;
  const int b = blockIdx.x;
  h[t] = 0; h[t + 256] = 0;
  __syncthreads();
  const int lo = b * chunk;
  const int hi = min(lo + chunk, ET);
  for (int i = lo + t; i < hi; i += 256) {
    int d = (i < E) ? ei[E + i] : (i - E);
    atomicAdd(&h[d >> BSHIFT], 1);
  }
  __syncthreads();
  for (int k = t; k < nbuck; k += 256) gh[k * NBLK + b] = h[k];
}

__global__ __launch_bounds__(256) void bucket_scatter_kernel(
    const int* __restrict__ ei, const int* __restrict__ ghp,
    const int* __restrict__ bsum, unsigned* __restrict__ pairs,
    int E, int ET, int nbuck, int chunk) {
  __shared__ int cur[512];
  const int t = threadIdx.x;
  const int b = blockIdx.x;
  for (int k = t; k < nbuck; k += 256) {
    int idx = k * NBLK + b;
    cur[k] = ghp[idx] + bsum[idx >> 10];
  }
  __syncthreads();
  const int lo = b * chunk;
  const int hi = min(lo + chunk, ET);
  for (int i = lo + t; i < hi; i += 256) {
    int s, d;
    if (i < E) { s = ei[i]; d = ei[E + i]; } else { s = d = i - E; }
    int pos = atomicAdd(&cur[d >> BSHIFT], 1);
    pairs[pos] = ((unsigned)s << 8) | (unsigned)(d & 255);
  }
}

__global__ __launch_bounds__(256) void bucket_finalize_kernel(
    const unsigned* __restrict__ pairs, const int* __restrict__ ghp,
    const int* __restrict__ bsum, int* __restrict__ row_ptr,
    int* __restrict__ esrc, int N, int ET, int nbuck) {
  __shared__ int hist[256];
  __shared__ int cur[256];
  __shared__ int sd[256];
  const int t = threadIdx.x;
  const int k = blockIdx.x;
  const int node0 = k << BSHIFT;
  const int idx0 = k * NBLK;
  const int base = ghp[idx0] + bsum[idx0 >> 10];
  int end;
  if (k + 1 < nbuck) {
    const int idx1 = (k + 1) * NBLK;
    end = ghp[idx1] + bsum[idx1 >> 10];
  } else {
    end = ET;
  }
  hist[t] = 0;
  __syncthreads();
  for (int e = base + t; e < end; e += 256) {
    atomicAdd(&hist[pairs[e] & 255u], 1);
  }
  __syncthreads();
  const int v = hist[t];
  __syncthreads();
  sd[t] = v;
  __syncthreads();
  for (int o = 1; o < 256; o <<= 1) {
    int x = (t >= o) ? sd[t - o] : 0;
    __syncthreads();
    sd[t] += x;
    __syncthreads();
  }
  const int excl = sd[t] - v;
  if (node0 + t < N) row_ptr[node0 + t] = base + excl;
  cur[t] = excl;
  __syncthreads();
  for (int e = base + t; e < end; e += 256) {
    unsigned p = pairs[e];
    int pos = atomicAdd(&cur[p & 255u], 1);
    esrc[base + pos] = (int)(p >> 8);
  }
  if (k == 0 && t == 0) row_ptr[N] = ET;
}

// ---------------- W fragment prepack (both layers, one launch) ----------------
// frag layout: [kstep(4)][tile(9)][lane(64)][elem(8)] fp16.
// tile t covers cols 16t+0..15 of B' = [W | log2e*W@a_src^T | log2e*W@a_dst^T | pad].
__global__ __launch_bounds__(256) void pack_w_kernel(
    const float* __restrict__ W1, const float* __restrict__ as1,
    const float* __restrict__ ad1, __half* __restrict__ frag1,
    const float* __restrict__ W2, const float* __restrict__ as2,
    const float* __restrict__ ad2, __half* __restrict__ frag2) {
  const float LOG2E = 1.4426950408889634f;
  int tid = blockIdx.x * 256 + threadIdx.x;
  const int PER = 4 * 9 * 64;
  if (tid >= 2 * PER) return;
  const bool second = tid >= PER;
  if (second) tid -= PER;
  const float* W = second ? W2 : W1;
  const float* a_src = second ? as2 : as1;
  const float* a_dst = second ? ad2 : ad1;
  __half* frag = second ? frag2 : frag1;
  int lane = tid & 63;
  int tile = (tid >> 6) % 9;
  int ks = tid / (9 * 64);
  int li = lane & 15, hi = lane >> 4;
  int col = tile * 16 + li;
  __half* dst = frag + (size_t)tid * 8;
  for (int i = 0; i < 8; ++i) {
    int k = ks * 32 + hi * 8 + i;
    float v = 0.f;
    if (col < 128) {
      v = W[k * 128 + col];
    } else if (col < 132) {
      int h = col - 128;
      float s = 0.f;
      for (int j = 0; j < 32; ++j) s += W[k * 128 + h * 32 + j] * a_src[h * 32 + j];
      v = s * LOG2E;
    } else if (col < 136) {
      int h = col - 132;
      float s = 0.f;
      for (int j = 0; j < 32; ++j) s += W[k * 128 + h * 32 + j] * a_dst[h * 32 + j];
      v = s * LOG2E;
    }
    dst[i] = __float2half(v);
  }
}

// ---------------- MFMA GEMM: h = in @ W (+ fused alpha columns) ----------------
// Fragment table (36 KB) staged in LDS once per block; waves grid-stride over
// 16-row tiles reading frags via ds_read_b128 (consecutive lanes, consecutive
// 16B -> max-throughput pattern). Only the x-row comes from global per tile.
template <bool F32IN>
__global__ __launch_bounds__(256) void gemm_mfma_kernel(
    const void* __restrict__ in, const __half* __restrict__ frag,
    __half* __restrict__ hout, float* __restrict__ as_out, float* __restrict__ ad_out,
    int nrows) {
  __shared__ __half lfrag[36 * 64 * 8];  // 36,864 B
  const int t = threadIdx.x;
  // stage 2304 f16x8 entries, 9 per thread, coalesced
  {
    f16x8* lf = (f16x8*)lfrag;
    const f16x8* gf = (const f16x8*)frag;
#pragma unroll
    for (int k = 0; k < 9; ++k) {
      const int id = k * 256 + t;
      lf[id] = gf[id];
    }
  }
  __syncthreads();

  const int lane = t & 63;
  const int li = lane & 15, hi = lane >> 4;
  const int ntiles = (nrows + 15) >> 4;
  const int nwaves = gridDim.x << 2;
  const f16x8* lf = (const f16x8*)lfrag;

  for (int tile = (blockIdx.x * 256 + t) >> 6; tile < ntiles; tile += nwaves) {
    int row = tile * 16 + li;
    const bool valid = row < nrows;
    const int r = valid ? row : nrows - 1;  // safe load, stores predicated

    f32x4 acc[9];
#pragma unroll
    for (int q = 0; q < 9; ++q) acc[q] = (f32x4){0.f, 0.f, 0.f, 0.f};

#pragma unroll
    for (int ks = 0; ks < 4; ++ks) {
      f16x8 xf;
      if (F32IN) {
        const float* xp = (const float*)in + (size_t)r * FEAT + ks * 32 + hi * 8;
        float4 v0 = *(const float4*)xp;
        float4 v1 = *(const float4*)(xp + 4);
        xf[0] = (_Float16)v0.x; xf[1] = (_Float16)v0.y;
        xf[2] = (_Float16)v0.z; xf[3] = (_Float16)v0.w;
        xf[4] = (_Float16)v1.x; xf[5] = (_Float16)v1.y;
        xf[6] = (_Float16)v1.z; xf[7] = (_Float16)v1.w;
      } else {
        xf = *(const f16x8*)((const __half*)in + (size_t)r * FEAT + ks * 32 + hi * 8);
      }
#pragma unroll
      for (int q = 0; q < 9; ++q) {
        const f16x8 wf = lf[(ks * 9 + q) * 64 + lane];
        acc[q] = __builtin_amdgcn_mfma_f32_16x16x32_f16(wf, xf, acc[q], 0, 0, 0);
      }
    }

    if (valid) {
#pragma unroll
      for (int q = 0; q < 8; ++q) {
        union { __half2 h[2]; uint2 u; } pk;
        pk.h[0] = __floats2half2_rn(acc[q][0], acc[q][1]);
        pk.h[1] = __floats2half2_rn(acc[q][2], acc[q][3]);
        *(uint2*)(hout + (size_t)r * FEAT + q * 16 + hi * 4) = pk.u;
      }
      if (hi == 0) *(float4*)(as_out + r * 4) = make_float4(acc[8][0], acc[8][1], acc[8][2], acc[8][3]);
      if (hi == 1) *(float4*)(ad_out + r * 4) = make_float4(acc[8][0], acc[8][1], acc[8][2], acc[8][3]);
    }
  }
}

// ---------------- per-node softmax + aggregation ----------------
// Round-8 structure (8-deep gather chunks, u32 saddr addressing, exp2; alphas
// pre-scaled by log2e in pack_w). This kernel is at its measured gather
// roofline (~3.0 TB/s L2-fill; r7/r9/r10 falsified crossbar/VALU/concurrency).
__device__ __forceinline__ void gat_accum(
    const int* __restrict__ esrc, const float* __restrict__ as_,
    const __half2* __restrict__ h, float adv, unsigned hd, unsigned lofs,
    int e, int end, float2& a2, float& den) {
  for (; e + 7 < end; e += 8) {
    unsigned s[8];
#pragma unroll
    for (int i = 0; i < 8; ++i) s[i] = (unsigned)esrc[e + i];
    float as8[8];
#pragma unroll
    for (int i = 0; i < 8; ++i) as8[i] = as_[s[i] * 4u + hd];
    __half2 hv[8];
#pragma unroll
    for (int i = 0; i < 8; ++i) hv[i] = h[((size_t)s[i] << 6) | lofs];
#pragma unroll
    for (int i = 0; i < 8; ++i) {
      const float x = as8[i] + adv;
      const float w = __builtin_amdgcn_exp2f(fmaxf(x, 0.2f * x));
      den += w;
      a2.x = fmaf(__half2float(hv[i].x), w, a2.x);
      a2.y = fmaf(__half2float(hv[i].y), w, a2.y);
    }
  }
  for (; e + 3 < end; e += 4) {
    unsigned s[4];
#pragma unroll
    for (int i = 0; i < 4; ++i) s[i] = (unsigned)esrc[e + i];
    float as4[4];
#pragma unroll
    for (int i = 0; i < 4; ++i) as4[i] = as_[s[i] * 4u + hd];
    __half2 hv[4];
#pragma unroll
    for (int i = 0; i < 4; ++i) hv[i] = h[((size_t)s[i] << 6) | lofs];
#pragma unroll
    for (int i = 0; i < 4; ++i) {
      const float x = as4[i] + adv;
      const float w = __builtin_amdgcn_exp2f(fmaxf(x, 0.2f * x));
      den += w;
      a2.x = fmaf(__half2float(hv[i].x), w, a2.x);
      a2.y = fmaf(__half2float(hv[i].y), w, a2.y);
    }
  }
  for (; e < end; ++e) {
    const unsigned s0 = (unsigned)esrc[e];
    const float x = as_[s0 * 4u + hd] + adv;
    const float w = __builtin_amdgcn_exp2f(fmaxf(x, 0.2f * x));
    const __half2 h0 = h[((size_t)s0 << 6) | lofs];
    den += w;
    a2.x = fmaf(__half2float(h0.x), w, a2.x);
    a2.y = fmaf(__half2float(h0.y), w, a2.y);
  }
}

// One wave per node. MODE 0: fp16 elu(agg+bias). MODE 1: fused FC head.
template <int MODE>
__global__ __launch_bounds__(256) void node_gat_kernel(
    const int* __restrict__ row_ptr, const int* __restrict__ esrc,
    const float* __restrict__ as_, const float* __restrict__ ad_,
    const __half2* __restrict__ h, const float* __restrict__ bias,
    __half2* __restrict__ out16, const float* __restrict__ fcw,
    const float* __restrict__ fcb, float* __restrict__ outf, int n) {
  const int wid = (blockIdx.x * 256 + threadIdx.x) >> 6;
  if (wid >= n) return;
  const int l = threadIdx.x & 63;
  const unsigned hd = (unsigned)(l >> 4);
  const unsigned lofs = (unsigned)l;
  const int begin = row_ptr[wid];
  const int end = row_ptr[wid + 1];
  const float adv = ad_[(unsigned)wid * 4u + hd];

  float2 a2 = make_float2(0.f, 0.f);
  float den = 0.f;
  gat_accum(esrc, as_, h, adv, hd, lofs, begin, end, a2, den);

  const float inv = 1.0f / (den + 1e-16f);
  const float o0 = a2.x * inv;
  const float o1 = a2.y * inv;
  const float2 b = *(const float2*)(bias + l * 2);
  if (MODE == 0) {
    out16[((size_t)(unsigned)wid << 6) | lofs] =
        __floats2half2_rn(eluf(o0 + b.x), eluf(o1 + b.y));
  } else {
    const float e0 = eluf(o0 + b.x);
    const float e1 = eluf(o1 + b.y);
    const float4 w4 = *(const float4*)(fcw + l * 4);  // Wfc[2l][0..1], Wfc[2l+1][0..1]
    float s0 = e0 * w4.x + e1 * w4.z;
    float s1 = e0 * w4.y + e1 * w4.w;
#pragma unroll
    for (int o = 32; o >= 1; o >>= 1) {
      s0 += __shfl_xor(s0, o);
      s1 += __shfl_xor(s1, o);
    }
    if (l == 0) {
      *(float2*)(outf + (size_t)wid * 2) = make_float2(s0 + fcb[0], s1 + fcb[1]);
    }
  }
}

extern "C" void kernel_launch(void* const* d_in, const int* in_sizes, int n_in,
                              void* d_out, int out_size, void* d_ws, size_t ws_size,
                              hipStream_t stream) {
  const float* x   = (const float*)d_in[0];
  const int*   ei  = (const int*)d_in[1];
  const float* W1  = (const float*)d_in[2];
  const float* as1 = (const float*)d_in[3];
  const float* ad1 = (const float*)d_in[4];
  const float* b1  = (const float*)d_in[5];
  const float* W2  = (const float*)d_in[6];
  const float* as2 = (const float*)d_in[7];
  const float* ad2 = (const float*)d_in[8];
  const float* b2  = (const float*)d_in[9];
  const float* Wfc = (const float*)d_in[10];
  const float* bfc = (const float*)d_in[11];
  float* out = (float*)d_out;

  const int N = in_sizes[0] / FEAT;
  const int E = in_sizes[1] / 2;
  const int ET = E + N;
  const int nbuck = (N + 255) >> BSHIFT;     // buckets of 256 nodes
  const int NN = nbuck * NBLK;               // gh array length
  const int chunk = (ET + NBLK - 1) / NBLK;

  // workspace layout
  char* ws = (char*)d_ws;
  __half* hraw = (__half*)ws;                               // N*128 fp16
  __half* hin2 = hraw + (size_t)N * FEAT;                   // N*128 fp16
  float* acc   = (float*)(hin2 + (size_t)N * FEAT);         // N*128 f32 (CSR scratch)
  float* asb   = acc + (size_t)N * FEAT;                    // N*4
  float* adb   = asb + (size_t)N * 4;                       // N*4
  __half* bfrag1 = (__half*)(adb + (size_t)N * 4);          // 4*9*64*8 fp16
  __half* bfrag2 = bfrag1 + 4 * 9 * 64 * 8;                 // 4*9*64*8 fp16
  int* bsum    = (int*)(bfrag2 + 4 * 9 * 64 * 8);           // 256
  int* row_ptr = bsum + 256;                                // N+1
  int* esrc    = row_ptr + (N + 1);                         // ET
  // CSR-build scratch aliased into acc region (dead after finalize):
  int* gh    = (int*)acc;                                   // NN
  int* ghp   = gh + NN;                                     // NN
  unsigned* pairs = (unsigned*)(ghp + NN);                  // ET

  const dim3 b256(256);
  const int nb = (NN + 1023) / 1024;

  // ---- prepack W fragments (both layers, one launch) ----
  pack_w_kernel<<<18, b256, 0, stream>>>(W1, as1, ad1, bfrag1, W2, as2, ad2, bfrag2);

  // ---- bucketed CSR build ----
  bucket_hist_kernel<<<NBLK, b256, 0, stream>>>(ei, gh, E, ET, nbuck, chunk);
  scan1_kernel<<<nb, b256, 0, stream>>>(gh, ghp, bsum, NN);
  scan2_kernel<<<1, b256, 0, stream>>>(bsum, nb);
  bucket_scatter_kernel<<<NBLK, b256, 0, stream>>>(ei, ghp, bsum, pairs, E, ET, nbuck, chunk);
  bucket_finalize_kernel<<<nbuck, b256, 0, stream>>>(pairs, ghp, bsum, row_ptr, esrc, N, ET, nbuck);

  const int ggrid = 256;                       // LDS-staged gemm, grid-stride tiles
  const int wgrid = (N * 64 + 255) / 256;      // one wave per node

  // ---- layer 1 ----
  gemm_mfma_kernel<true><<<ggrid, b256, 0, stream>>>(x, bfrag1, hraw, asb, adb, N);
  node_gat_kernel<0><<<wgrid, b256, 0, stream>>>(row_ptr, esrc, asb, adb,
                                                 (const __half2*)hraw, b1,
                                                 (__half2*)hin2, nullptr, nullptr, nullptr, N);

  // ---- layer 2 (FC head fused) ----
  gemm_mfma_kernel<false><<<ggrid, b256, 0, stream>>>(hin2, bfrag2, hraw, asb, adb, N);
  node_gat_kernel<1><<<wgrid, b256, 0, stream>>>(row_ptr, esrc, asb, adb,
                                                 (const __half2*)hraw, b2,
                                                 nullptr, Wfc, bfc, out, N);
}

// Round 12
// 236.541 us; speedup vs baseline: 1.1786x; 1.0507x over previous
//
#include <hip/hip_runtime.h>
#include <hip/hip_fp16.h>
#include <math.h>

#define FEAT 128
#define NBLK 256       // blocks for bucket hist/scatter
#define BSHIFT 8       // bucket = dst >> 8 (256 nodes per bucket)

typedef _Float16 f16x8 __attribute__((ext_vector_type(8)));
typedef float f32x4 __attribute__((ext_vector_type(4)));

__device__ __forceinline__ float eluf(float x) {
  return x > 0.0f ? x : (__expf(x) - 1.0f);
}

// ---------------- generic scan kernels (1024 elems/block) ----------------

__global__ __launch_bounds__(256) void scan1_kernel(const int* __restrict__ cnt,
                                                    int* __restrict__ pre,
                                                    int* __restrict__ bsum, int n) {
  __shared__ int sd[256];
  const int t = threadIdx.x;
  const int idx = blockIdx.x * 1024 + t * 4;
  int4 v = make_int4(0, 0, 0, 0);
  if (idx + 3 < n) {
    v = *(const int4*)(cnt + idx);
  } else {
    if (idx < n)     v.x = cnt[idx];
    if (idx + 1 < n) v.y = cnt[idx + 1];
    if (idx + 2 < n) v.z = cnt[idx + 2];
    if (idx + 3 < n) v.w = cnt[idx + 3];
  }
  const int tsum = v.x + v.y + v.z + v.w;
  sd[t] = tsum;
  __syncthreads();
  for (int o = 1; o < 256; o <<= 1) {
    int x = (t >= o) ? sd[t - o] : 0;
    __syncthreads();
    sd[t] += x;
    __syncthreads();
  }
  const int excl = sd[t] - tsum;
  if (idx < n)     pre[idx]     = excl;
  if (idx + 1 < n) pre[idx + 1] = excl + v.x;
  if (idx + 2 < n) pre[idx + 2] = excl + v.x + v.y;
  if (idx + 3 < n) pre[idx + 3] = excl + v.x + v.y + v.z;
  if (t == 255) bsum[blockIdx.x] = sd[255];
}

__global__ __launch_bounds__(256) void scan2_kernel(int* __restrict__ bsum, int nb) {
  __shared__ int sd[256];
  const int t = threadIdx.x;
  int v = (t < nb) ? bsum[t] : 0;
  sd[t] = v;
  __syncthreads();
  for (int o = 1; o < 256; o <<= 1) {
    int x = (t >= o) ? sd[t - o] : 0;
    __syncthreads();
    sd[t] += x;
    __syncthreads();
  }
  if (t < nb) bsum[t] = sd[t] - v;
}

// ---------------- bucketed CSR build (+ fused W prepack) ----------------
// Blocks [0, NBLK): per-block LDS histogram over dst buckets.
// Blocks [NBLK, NBLK+18): W fragment prepack for both layers (independent work).
// frag layout: [kstep(4)][tile(9)][lane(64)][elem(8)] fp16; tile t covers cols
// 16t+0..15 of B' = [W | log2e*W@a_src^T | log2e*W@a_dst^T | pad] (alpha columns
// pre-scaled by log2e so node_gat uses exp2; lrelu is positively homogeneous).
__global__ __launch_bounds__(256) void hist_pack_kernel(
    const int* __restrict__ ei, int* __restrict__ gh,
    int E, int ET, int nbuck, int chunk,
    const float* __restrict__ W1, const float* __restrict__ as1,
    const float* __restrict__ ad1, __half* __restrict__ frag1,
    const float* __restrict__ W2, const float* __restrict__ as2,
    const float* __restrict__ ad2, __half* __restrict__ frag2) {
  __shared__ int h[512];
  const int t = threadIdx.x;
  const int b = blockIdx.x;
  if (b < NBLK) {
    h[t] = 0; h[t + 256] = 0;
    __syncthreads();
    const int lo = b * chunk;
    const int hi = min(lo + chunk, ET);
    for (int i = lo + t; i < hi; i += 256) {
      int d = (i < E) ? ei[E + i] : (i - E);
      atomicAdd(&h[d >> BSHIFT], 1);
    }
    __syncthreads();
    for (int k = t; k < nbuck; k += 256) gh[k * NBLK + b] = h[k];
    return;
  }
  // ---- pack arm ----
  const float LOG2E = 1.4426950408889634f;
  int tid = (b - NBLK) * 256 + t;
  const int PER = 4 * 9 * 64;
  if (tid >= 2 * PER) return;
  const bool second = tid >= PER;
  if (second) tid -= PER;
  const float* W = second ? W2 : W1;
  const float* a_src = second ? as2 : as1;
  const float* a_dst = second ? ad2 : ad1;
  __half* frag = second ? frag2 : frag1;
  int lane = tid & 63;
  int tile = (tid >> 6) % 9;
  int ks = tid / (9 * 64);
  int li = lane & 15, hi = lane >> 4;
  int col = tile * 16 + li;
  __half* dst = frag + (size_t)tid * 8;
  for (int i = 0; i < 8; ++i) {
    int k = ks * 32 + hi * 8 + i;
    float v = 0.f;
    if (col < 128) {
      v = W[k * 128 + col];
    } else if (col < 132) {
      int hh = col - 128;
      float s = 0.f;
      for (int j = 0; j < 32; ++j) s += W[k * 128 + hh * 32 + j] * a_src[hh * 32 + j];
      v = s * LOG2E;
    } else if (col < 136) {
      int hh = col - 132;
      float s = 0.f;
      for (int j = 0; j < 32; ++j) s += W[k * 128 + hh * 32 + j] * a_dst[hh * 32 + j];
      v = s * LOG2E;
    }
    dst[i] = __float2half(v);
  }
}

__global__ __launch_bounds__(256) void bucket_scatter_kernel(
    const int* __restrict__ ei, const int* __restrict__ ghp,
    const int* __restrict__ bsum, unsigned* __restrict__ pairs,
    int E, int ET, int nbuck, int chunk) {
  __shared__ int cur[512];
  const int t = threadIdx.x;
  const int b = blockIdx.x;
  for (int k = t; k < nbuck; k += 256) {
    int idx = k * NBLK + b;
    cur[k] = ghp[idx] + bsum[idx >> 10];
  }
  __syncthreads();
  const int lo = b * chunk;
  const int hi = min(lo + chunk, ET);
  for (int i = lo + t; i < hi; i += 256) {
    int s, d;
    if (i < E) { s = ei[i]; d = ei[E + i]; } else { s = d = i - E; }
    int pos = atomicAdd(&cur[d >> BSHIFT], 1);
    pairs[pos] = ((unsigned)s << 8) | (unsigned)(d & 255);
  }
}

__global__ __launch_bounds__(256) void bucket_finalize_kernel(
    const unsigned* __restrict__ pairs, const int* __restrict__ ghp,
    const int* __restrict__ bsum, int* __restrict__ row_ptr,
    int* __restrict__ esrc, int N, int ET, int nbuck) {
  __shared__ int hist[256];
  __shared__ int cur[256];
  __shared__ int sd[256];
  const int t = threadIdx.x;
  const int k = blockIdx.x;
  const int node0 = k << BSHIFT;
  const int idx0 = k * NBLK;
  const int base = ghp[idx0] + bsum[idx0 >> 10];
  int end;
  if (k + 1 < nbuck) {
    const int idx1 = (k + 1) * NBLK;
    end = ghp[idx1] + bsum[idx1 >> 10];
  } else {
    end = ET;
  }
  hist[t] = 0;
  __syncthreads();
  for (int e = base + t; e < end; e += 256) {
    atomicAdd(&hist[pairs[e] & 255u], 1);
  }
  __syncthreads();
  const int v = hist[t];
  __syncthreads();
  sd[t] = v;
  __syncthreads();
  for (int o = 1; o < 256; o <<= 1) {
    int x = (t >= o) ? sd[t - o] : 0;
    __syncthreads();
    sd[t] += x;
    __syncthreads();
  }
  const int excl = sd[t] - v;
  if (node0 + t < N) row_ptr[node0 + t] = base + excl;
  cur[t] = excl;
  __syncthreads();
  for (int e = base + t; e < end; e += 256) {
    unsigned p = pairs[e];
    int pos = atomicAdd(&cur[p & 255u], 1);
    esrc[base + pos] = (int)(p >> 8);
  }
  if (k == 0 && t == 0) row_ptr[N] = ET;
}

// ---------------- MFMA GEMM: h = in @ W (+ fused alpha columns) ----------------
// Fragment table (36 KB) staged in LDS once per block; waves grid-stride over
// 16-row tiles reading frags via ds_read_b128. Only x-rows come from global.
template <bool F32IN>
__global__ __launch_bounds__(256) void gemm_mfma_kernel(
    const void* __restrict__ in, const __half* __restrict__ frag,
    __half* __restrict__ hout, float* __restrict__ as_out, float* __restrict__ ad_out,
    int nrows) {
  __shared__ __half lfrag[36 * 64 * 8];  // 36,864 B
  const int t = threadIdx.x;
  {
    f16x8* lf = (f16x8*)lfrag;
    const f16x8* gf = (const f16x8*)frag;
#pragma unroll
    for (int k = 0; k < 9; ++k) {
      const int id = k * 256 + t;
      lf[id] = gf[id];
    }
  }
  __syncthreads();

  const int lane = t & 63;
  const int li = lane & 15, hi = lane >> 4;
  const int ntiles = (nrows + 15) >> 4;
  const int nwaves = gridDim.x << 2;
  const f16x8* lf = (const f16x8*)lfrag;

  for (int tile = (blockIdx.x * 256 + t) >> 6; tile < ntiles; tile += nwaves) {
    int row = tile * 16 + li;
    const bool valid = row < nrows;
    const int r = valid ? row : nrows - 1;  // safe load, stores predicated

    f32x4 acc[9];
#pragma unroll
    for (int q = 0; q < 9; ++q) acc[q] = (f32x4){0.f, 0.f, 0.f, 0.f};

#pragma unroll
    for (int ks = 0; ks < 4; ++ks) {
      f16x8 xf;
      if (F32IN) {
        const float* xp = (const float*)in + (size_t)r * FEAT + ks * 32 + hi * 8;
        float4 v0 = *(const float4*)xp;
        float4 v1 = *(const float4*)(xp + 4);
        xf[0] = (_Float16)v0.x; xf[1] = (_Float16)v0.y;
        xf[2] = (_Float16)v0.z; xf[3] = (_Float16)v0.w;
        xf[4] = (_Float16)v1.x; xf[5] = (_Float16)v1.y;
        xf[6] = (_Float16)v1.z; xf[7] = (_Float16)v1.w;
      } else {
        xf = *(const f16x8*)((const __half*)in + (size_t)r * FEAT + ks * 32 + hi * 8);
      }
#pragma unroll
      for (int q = 0; q < 9; ++q) {
        const f16x8 wf = lf[(ks * 9 + q) * 64 + lane];
        acc[q] = __builtin_amdgcn_mfma_f32_16x16x32_f16(wf, xf, acc[q], 0, 0, 0);
      }
    }

    if (valid) {
#pragma unroll
      for (int q = 0; q < 8; ++q) {
        union { __half2 h[2]; uint2 u; } pk;
        pk.h[0] = __floats2half2_rn(acc[q][0], acc[q][1]);
        pk.h[1] = __floats2half2_rn(acc[q][2], acc[q][3]);
        *(uint2*)(hout + (size_t)r * FEAT + q * 16 + hi * 4) = pk.u;
      }
      if (hi == 0) *(float4*)(as_out + r * 4) = make_float4(acc[8][0], acc[8][1], acc[8][2], acc[8][3]);
      if (hi == 1) *(float4*)(ad_out + r * 4) = make_float4(acc[8][0], acc[8][1], acc[8][2], acc[8][3]);
    }
  }
}

// ---------------- per-node softmax + aggregation ----------------
// Round-8 structure (8-deep gather chunks, u32 saddr addressing, exp2; alphas
// pre-scaled by log2e). At its measured gather roofline (~3.0 TB/s L2-fill;
// r7/r9/r10 falsified crossbar/VALU/concurrency as levers).
__device__ __forceinline__ void gat_accum(
    const int* __restrict__ esrc, const float* __restrict__ as_,
    const __half2* __restrict__ h, float adv, unsigned hd, unsigned lofs,
    int e, int end, float2& a2, float& den) {
  for (; e + 7 < end; e += 8) {
    unsigned s[8];
#pragma unroll
    for (int i = 0; i < 8; ++i) s[i] = (unsigned)esrc[e + i];
    float as8[8];
#pragma unroll
    for (int i = 0; i < 8; ++i) as8[i] = as_[s[i] * 4u + hd];
    __half2 hv[8];
#pragma unroll
    for (int i = 0; i < 8; ++i) hv[i] = h[((size_t)s[i] << 6) | lofs];
#pragma unroll
    for (int i = 0; i < 8; ++i) {
      const float x = as8[i] + adv;
      const float w = __builtin_amdgcn_exp2f(fmaxf(x, 0.2f * x));
      den += w;
      a2.x = fmaf(__half2float(hv[i].x), w, a2.x);
      a2.y = fmaf(__half2float(hv[i].y), w, a2.y);
    }
  }
  for (; e + 3 < end; e += 4) {
    unsigned s[4];
#pragma unroll
    for (int i = 0; i < 4; ++i) s[i] = (unsigned)esrc[e + i];
    float as4[4];
#pragma unroll
    for (int i = 0; i < 4; ++i) as4[i] = as_[s[i] * 4u + hd];
    __half2 hv[4];
#pragma unroll
    for (int i = 0; i < 4; ++i) hv[i] = h[((size_t)s[i] << 6) | lofs];
#pragma unroll
    for (int i = 0; i < 4; ++i) {
      const float x = as4[i] + adv;
      const float w = __builtin_amdgcn_exp2f(fmaxf(x, 0.2f * x));
      den += w;
      a2.x = fmaf(__half2float(hv[i].x), w, a2.x);
      a2.y = fmaf(__half2float(hv[i].y), w, a2.y);
    }
  }
  for (; e < end; ++e) {
    const unsigned s0 = (unsigned)esrc[e];
    const float x = as_[s0 * 4u + hd] + adv;
    const float w = __builtin_amdgcn_exp2f(fmaxf(x, 0.2f * x));
    const __half2 h0 = h[((size_t)s0 << 6) | lofs];
    den += w;
    a2.x = fmaf(__half2float(h0.x), w, a2.x);
    a2.y = fmaf(__half2float(h0.y), w, a2.y);
  }
}

// One wave per node. MODE 0: fp16 elu(agg+bias). MODE 1: fused FC head.
template <int MODE>
__global__ __launch_bounds__(256) void node_gat_kernel(
    const int* __restrict__ row_ptr, const int* __restrict__ esrc,
    const float* __restrict__ as_, const float* __restrict__ ad_,
    const __half2* __restrict__ h, const float* __restrict__ bias,
    __half2* __restrict__ out16, const float* __restrict__ fcw,
    const float* __restrict__ fcb, float* __restrict__ outf, int n) {
  const int wid = (blockIdx.x * 256 + threadIdx.x) >> 6;
  if (wid >= n) return;
  const int l = threadIdx.x & 63;
  const unsigned hd = (unsigned)(l >> 4);
  const unsigned lofs = (unsigned)l;
  const int begin = row_ptr[wid];
  const int end = row_ptr[wid + 1];
  const float adv = ad_[(unsigned)wid * 4u + hd];

  float2 a2 = make_float2(0.f, 0.f);
  float den = 0.f;
  gat_accum(esrc, as_, h, adv, hd, lofs, begin, end, a2, den);

  const float inv = 1.0f / (den + 1e-16f);
  const float o0 = a2.x * inv;
  const float o1 = a2.y * inv;
  const float2 b = *(const float2*)(bias + l * 2);
  if (MODE == 0) {
    out16[((size_t)(unsigned)wid << 6) | lofs] =
        __floats2half2_rn(eluf(o0 + b.x), eluf(o1 + b.y));
  } else {
    const float e0 = eluf(o0 + b.x);
    const float e1 = eluf(o1 + b.y);
    const float4 w4 = *(const float4*)(fcw + l * 4);  // Wfc[2l][0..1], Wfc[2l+1][0..1]
    float s0 = e0 * w4.x + e1 * w4.z;
    float s1 = e0 * w4.y + e1 * w4.w;
#pragma unroll
    for (int o = 32; o >= 1; o >>= 1) {
      s0 += __shfl_xor(s0, o);
      s1 += __shfl_xor(s1, o);
    }
    if (l == 0) {
      *(float2*)(outf + (size_t)wid * 2) = make_float2(s0 + fcb[0], s1 + fcb[1]);
    }
  }
}

extern "C" void kernel_launch(void* const* d_in, const int* in_sizes, int n_in,
                              void* d_out, int out_size, void* d_ws, size_t ws_size,
                              hipStream_t stream) {
  const float* x   = (const float*)d_in[0];
  const int*   ei  = (const int*)d_in[1];
  const float* W1  = (const float*)d_in[2];
  const float* as1 = (const float*)d_in[3];
  const float* ad1 = (const float*)d_in[4];
  const float* b1  = (const float*)d_in[5];
  const float* W2  = (const float*)d_in[6];
  const float* as2 = (const float*)d_in[7];
  const float* ad2 = (const float*)d_in[8];
  const float* b2  = (const float*)d_in[9];
  const float* Wfc = (const float*)d_in[10];
  const float* bfc = (const float*)d_in[11];
  float* out = (float*)d_out;

  const int N = in_sizes[0] / FEAT;
  const int E = in_sizes[1] / 2;
  const int ET = E + N;
  const int nbuck = (N + 255) >> BSHIFT;     // buckets of 256 nodes
  const int NN = nbuck * NBLK;               // gh array length
  const int chunk = (ET + NBLK - 1) / NBLK;

  // workspace layout
  char* ws = (char*)d_ws;
  __half* hraw = (__half*)ws;                               // N*128 fp16
  __half* hin2 = hraw + (size_t)N * FEAT;                   // N*128 fp16
  float* acc   = (float*)(hin2 + (size_t)N * FEAT);         // N*128 f32 (CSR scratch)
  float* asb   = acc + (size_t)N * FEAT;                    // N*4
  float* adb   = asb + (size_t)N * 4;                       // N*4
  __half* bfrag1 = (__half*)(adb + (size_t)N * 4);          // 4*9*64*8 fp16
  __half* bfrag2 = bfrag1 + 4 * 9 * 64 * 8;                 // 4*9*64*8 fp16
  int* bsum    = (int*)(bfrag2 + 4 * 9 * 64 * 8);           // 256
  int* row_ptr = bsum + 256;                                // N+1
  int* esrc    = row_ptr + (N + 1);                         // ET
  // CSR-build scratch aliased into acc region (dead after finalize):
  int* gh    = (int*)acc;                                   // NN
  int* ghp   = gh + NN;                                     // NN
  unsigned* pairs = (unsigned*)(ghp + NN);                  // ET

  const dim3 b256(256);
  const int nb = (NN + 1023) / 1024;

  // ---- bucketed CSR build (hist fused with W prepack) ----
  hist_pack_kernel<<<NBLK + 18, b256, 0, stream>>>(ei, gh, E, ET, nbuck, chunk,
                                                   W1, as1, ad1, bfrag1,
                                                   W2, as2, ad2, bfrag2);
  scan1_kernel<<<nb, b256, 0, stream>>>(gh, ghp, bsum, NN);
  scan2_kernel<<<1, b256, 0, stream>>>(bsum, nb);
  bucket_scatter_kernel<<<NBLK, b256, 0, stream>>>(ei, ghp, bsum, pairs, E, ET, nbuck, chunk);
  bucket_finalize_kernel<<<nbuck, b256, 0, stream>>>(pairs, ghp, bsum, row_ptr, esrc, N, ET, nbuck);

  const int ggrid = 512;                       // LDS-staged gemm, grid-stride tiles
  const int wgrid = (N * 64 + 255) / 256;      // one wave per node

  // ---- layer 1 ----
  gemm_mfma_kernel<true><<<ggrid, b256, 0, stream>>>(x, bfrag1, hraw, asb, adb, N);
  node_gat_kernel<0><<<wgrid, b256, 0, stream>>>(row_ptr, esrc, asb, adb,
                                                 (const __half2*)hraw, b1,
                                                 (__half2*)hin2, nullptr, nullptr, nullptr, N);

  // ---- layer 2 (FC head fused) ----
  gemm_mfma_kernel<false><<<ggrid, b256, 0, stream>>>(hin2, bfrag2, hraw, asb, adb, N);
  node_gat_kernel<1><<<wgrid, b256, 0, stream>>>(row_ptr, esrc, asb, adb,
                                                 (const __half2*)hraw, b2,
                                                 nullptr, Wfc, bfc, out, N);
}